// Round 1
// baseline (3393.200 us; speedup 1.0000x reference)
//
#include <hip/hip_runtime.h>
#include <hip/hip_bf16.h>

#define N_NODES 50000
#define D_IN 128
#define HID 32
#define HEADS 8
#define NEG_SLOPE 0.2f

// ---------------- small precompute: wc = fold(W_dst, a_dst) ----------------
// wc1[k][h] = sum_c W1_dst[k][h*32+c] * a1_dst[h][c]   (k<128, h<8)
__global__ void wc1_kernel(const float* __restrict__ W1_dst,
                           const float* __restrict__ a1_dst,
                           float* __restrict__ wc1) {
    int i = blockIdx.x * blockDim.x + threadIdx.x;
    if (i >= 128 * 8) return;
    int k = i >> 3, h = i & 7;
    float s = 0.f;
#pragma unroll
    for (int c = 0; c < 32; ++c)
        s += W1_dst[k * 256 + h * 32 + c] * a1_dst[h * 32 + c];
    wc1[i] = s;
}

// wc2[k] = sum_c W2_dst[k][c] * a2_dst[c]   (k<256)
__global__ void wc2_kernel(const float* __restrict__ W2_dst,
                           const float* __restrict__ a2_dst,
                           float* __restrict__ wc2) {
    int k = blockIdx.x * blockDim.x + threadIdx.x;
    if (k >= 256) return;
    float s = 0.f;
#pragma unroll
    for (int c = 0; c < 32; ++c)
        s += W2_dst[k * 32 + c] * a2_dst[c];
    wc2[k] = s;
}

// ---------------- GEMM1: hs1 = x @ W1_src, + alpha_s1, alpha_d1 ------------
// block = 256 threads handles 4 nodes. Each thread owns output column c=tid,
// accumulates 4 nodes. W reads coalesced (k*256+c). Epilogue: 32-lane shuffle
// reduction for alpha_s; alpha_d from LDS x rows against folded wc1.
__global__ __launch_bounds__(256) void gemm1_kernel(
    const float* __restrict__ x, const float* __restrict__ W,
    const float* __restrict__ a_src, const float* __restrict__ wc1,
    float* __restrict__ hs1, float* __restrict__ alpha_s,
    float* __restrict__ alpha_d, int n) {
    __shared__ float xs[4][128];
    int node0 = blockIdx.x * 4;
    int tid = threadIdx.x;
    for (int i = tid; i < 4 * 128; i += 256) {
        int j = i >> 7, k = i & 127;
        int nn = node0 + j;
        xs[j][k] = (nn < n) ? x[(size_t)nn * 128 + k] : 0.f;
    }
    __syncthreads();
    float acc[4] = {0.f, 0.f, 0.f, 0.f};
    int c = tid;  // 0..255
#pragma unroll 8
    for (int k = 0; k < 128; ++k) {
        float w = W[k * 256 + c];
        acc[0] += xs[0][k] * w;
        acc[1] += xs[1][k] * w;
        acc[2] += xs[2][k] * w;
        acc[3] += xs[3][k] * w;
    }
    int h = c >> 5, cc = c & 31;
    float a = a_src[h * 32 + cc];
#pragma unroll
    for (int j = 0; j < 4; ++j) {
        int nn = node0 + j;
        if (nn < n) hs1[(size_t)nn * 256 + c] = acc[j];
        float p = acc[j] * a;
        for (int off = 16; off > 0; off >>= 1) p += __shfl_down(p, off, 32);
        if (cc == 0 && nn < n) alpha_s[nn * 8 + h] = p;
    }
    if (tid < 32) {
        int j = tid >> 3, hh = tid & 7;
        int nn = node0 + j;
        if (nn < n) {
            float s = 0.f;
            for (int k = 0; k < 128; ++k) s += xs[j][k] * wc1[k * 8 + hh];
            alpha_d[nn * 8 + hh] = s;
        }
    }
}

// ---------------- edge pass A (layer1): weights + denom --------------------
__global__ __launch_bounds__(256) void edge_denom1(
    const int* __restrict__ src, const int* __restrict__ dst,
    const float* __restrict__ as, const float* __restrict__ ad,
    float* __restrict__ ew, float* __restrict__ denom, int E) {
    int e = blockIdx.x * blockDim.x + threadIdx.x;
    if (e >= E) return;
    int s = src[e], d = dst[e];
    const float4* as4 = (const float4*)as;
    const float4* ad4 = (const float4*)ad;
    float4 s0 = as4[s * 2], s1 = as4[s * 2 + 1];
    float4 d0 = ad4[d * 2], d1 = ad4[d * 2 + 1];
    float v[8] = {s0.x + d0.x, s0.y + d0.y, s0.z + d0.z, s0.w + d0.w,
                  s1.x + d1.x, s1.y + d1.y, s1.z + d1.z, s1.w + d1.w};
    float w[8];
#pragma unroll
    for (int h = 0; h < 8; ++h) {
        float t = v[h];
        t = (t >= 0.f) ? t : NEG_SLOPE * t;
        w[h] = __expf(t);
        atomicAdd(&denom[d * 8 + h], w[h]);
    }
    float4* ew4 = (float4*)ew;
    ew4[e * 2] = make_float4(w[0], w[1], w[2], w[3]);
    ew4[e * 2 + 1] = make_float4(w[4], w[5], w[6], w[7]);
}

// ---------------- edge pass B (layer1): weighted scatter -------------------
// one 64-lane wave per edge; lane L handles channels 4L..4L+3 (head = L/8)
__global__ __launch_bounds__(256) void edge_scatter1(
    const int* __restrict__ src, const int* __restrict__ dst,
    const float* __restrict__ hs1, const float* __restrict__ ew,
    float* __restrict__ num, int E) {
    int gid = blockIdx.x * blockDim.x + threadIdx.x;
    int e = gid >> 6;
    int lane = threadIdx.x & 63;
    if (e >= E) return;
    int s = src[e], d = dst[e];
    float wt = ew[(size_t)e * 8 + (lane >> 3)];
    float4 v = ((const float4*)hs1)[(size_t)s * 64 + lane];
    float* o = num + (size_t)d * 256 + lane * 4;
    atomicAdd(o + 0, v.x * wt);
    atomicAdd(o + 1, v.y * wt);
    atomicAdd(o + 2, v.z * wt);
    atomicAdd(o + 3, v.w * wt);
}

// ---------------- finalize layer1: /denom + bias + relu (in place) ---------
__global__ __launch_bounds__(256) void finalize1(
    float* __restrict__ num, const float* __restrict__ denom,
    const float* __restrict__ b1, int n) {
    int i = blockIdx.x * blockDim.x + threadIdx.x;
    if (i >= n * 256) return;
    int nn = i >> 8, c = i & 255, h = c >> 5;
    float v = num[i] / (denom[nn * 8 + h] + 1e-16f) + b1[c];
    num[i] = (v > 0.f) ? v : 0.f;
}

// ---------------- GEMM2: hs2 = h1 @ W2_src, + alpha_s2, alpha_d2 -----------
// block = 256 threads = 8 nodes x 32 channels
__global__ __launch_bounds__(256) void gemm2_kernel(
    const float* __restrict__ h1, const float* __restrict__ W2,
    const float* __restrict__ a2_src, const float* __restrict__ wc2,
    float* __restrict__ hs2, float* __restrict__ alpha_s2,
    float* __restrict__ alpha_d2, int n) {
    __shared__ float xs[8][256];
    int node0 = blockIdx.x * 8;
    int tid = threadIdx.x;
    for (int i = tid; i < 8 * 256; i += 256) {
        int j = i >> 8, k = i & 255;
        int nn = node0 + j;
        xs[j][k] = (nn < n) ? h1[(size_t)nn * 256 + k] : 0.f;
    }
    __syncthreads();
    int j = tid >> 5, c = tid & 31;
    float acc = 0.f;
#pragma unroll 8
    for (int k = 0; k < 256; ++k) acc += xs[j][k] * W2[k * 32 + c];
    int nn = node0 + j;
    if (nn < n) hs2[(size_t)nn * 32 + c] = acc;
    float p = acc * a2_src[c];
    for (int off = 16; off > 0; off >>= 1) p += __shfl_down(p, off, 32);
    if (c == 0 && nn < n) alpha_s2[nn] = p;
    if (tid < 8) {
        int n2 = node0 + tid;
        if (n2 < n) {
            float s = 0.f;
            for (int k = 0; k < 256; ++k) s += xs[tid][k] * wc2[k];
            alpha_d2[n2] = s;
        }
    }
}

// ---------------- edge passes layer2 (heads=1) -----------------------------
__global__ __launch_bounds__(256) void edge_denom2(
    const int* __restrict__ src, const int* __restrict__ dst,
    const float* __restrict__ as, const float* __restrict__ ad,
    float* __restrict__ ew, float* __restrict__ denom, int E) {
    int e = blockIdx.x * blockDim.x + threadIdx.x;
    if (e >= E) return;
    int s = src[e], d = dst[e];
    float t = as[s] + ad[d];
    t = (t >= 0.f) ? t : NEG_SLOPE * t;
    float w = __expf(t);
    ew[e] = w;
    atomicAdd(&denom[d], w);
}

// 32 threads per edge, one channel each
__global__ __launch_bounds__(256) void edge_scatter2(
    const int* __restrict__ src, const int* __restrict__ dst,
    const float* __restrict__ hs2, const float* __restrict__ ew,
    float* __restrict__ num, int E) {
    int gid = blockIdx.x * blockDim.x + threadIdx.x;
    int e = gid >> 5;
    int c = gid & 31;
    if (e >= E) return;
    int s = src[e], d = dst[e];
    float wt = ew[e];
    atomicAdd(&num[(size_t)d * 32 + c], hs2[(size_t)s * 32 + c] * wt);
}

__global__ __launch_bounds__(256) void finalize2(
    const float* __restrict__ num, const float* __restrict__ denom,
    const float* __restrict__ b2, float* __restrict__ out, int n) {
    int i = blockIdx.x * blockDim.x + threadIdx.x;
    if (i >= n * 32) return;
    int nn = i >> 5, c = i & 31;
    out[i] = num[i] / (denom[nn] + 1e-16f) + b2[c];
}

extern "C" void kernel_launch(void* const* d_in, const int* in_sizes, int n_in,
                              void* d_out, int out_size, void* d_ws, size_t ws_size,
                              hipStream_t stream) {
    const float* x      = (const float*)d_in[0];
    const int*   eidx   = (const int*)d_in[1];
    const float* W1_src = (const float*)d_in[2];
    const float* W1_dst = (const float*)d_in[3];
    const float* a1_src = (const float*)d_in[4];
    const float* a1_dst = (const float*)d_in[5];
    const float* b1     = (const float*)d_in[6];
    const float* W2_src = (const float*)d_in[7];
    const float* W2_dst = (const float*)d_in[8];
    const float* a2_src = (const float*)d_in[9];
    // d_in[10] = a2_dst, d_in[11] = b2
    const float* a2_dst = (const float*)d_in[10];
    const float* b2     = (const float*)d_in[11];

    const int n = in_sizes[0] / D_IN;       // 50000
    const int E = in_sizes[1] / 2;          // 800000
    const int* src = eidx;
    const int* dst = eidx + E;

    float* ws = (float*)d_ws;
    size_t o = 0;
    float* hs1  = ws + o; o += (size_t)n * 256;
    float* num1 = ws + o; o += (size_t)n * 256;   // becomes h1 after finalize1
    float* ew1  = ws + o; o += (size_t)E * 8;
    float* as1  = ws + o; o += (size_t)n * 8;
    float* ad1  = ws + o; o += (size_t)n * 8;
    float* den1 = ws + o; o += (size_t)n * 8;
    float* wc1  = ws + o; o += 1024;
    float* hs2  = ws + o; o += (size_t)n * 32;
    float* num2 = ws + o; o += (size_t)n * 32;
    float* ew2  = ws + o; o += (size_t)E;
    float* as2  = ws + o; o += (size_t)n;
    float* ad2  = ws + o; o += (size_t)n;
    float* den2 = ws + o; o += (size_t)n;
    float* wc2  = ws + o; o += 256;

    // zero-init accumulators (ws is poisoned to 0xAA before each call)
    hipMemsetAsync(den1, 0, (size_t)n * 8 * sizeof(float), stream);
    hipMemsetAsync(num1, 0, (size_t)n * 256 * sizeof(float), stream);
    hipMemsetAsync(den2, 0, (size_t)n * sizeof(float), stream);
    hipMemsetAsync(num2, 0, (size_t)n * 32 * sizeof(float), stream);

    wc1_kernel<<<4, 256, 0, stream>>>(W1_dst, a1_dst, wc1);
    wc2_kernel<<<1, 256, 0, stream>>>(W2_dst, a2_dst, wc2);

    gemm1_kernel<<<(n + 3) / 4, 256, 0, stream>>>(x, W1_src, a1_src, wc1,
                                                  hs1, as1, ad1, n);
    edge_denom1<<<(E + 255) / 256, 256, 0, stream>>>(src, dst, as1, ad1,
                                                     ew1, den1, E);
    edge_scatter1<<<(E + 3) / 4, 256, 0, stream>>>(src, dst, hs1, ew1, num1, E);
    finalize1<<<(n * 256 + 255) / 256, 256, 0, stream>>>(num1, den1, b1, n);

    gemm2_kernel<<<(n + 7) / 8, 256, 0, stream>>>(num1, W2_src, a2_src, wc2,
                                                  hs2, as2, ad2, n);
    edge_denom2<<<(E + 255) / 256, 256, 0, stream>>>(src, dst, as2, ad2,
                                                     ew2, den2, E);
    edge_scatter2<<<((size_t)E * 32 + 255) / 256, 256, 0, stream>>>(src, dst, hs2,
                                                                    ew2, num2, E);
    finalize2<<<(n * 32 + 255) / 256, 256, 0, stream>>>(num2, den2, b2,
                                                        (float*)d_out, n);
}

// Round 2
// 493.430 us; speedup vs baseline: 6.8768x; 6.8768x over previous
//
#include <hip/hip_runtime.h>
#include <hip/hip_bf16.h>

#define D_IN 128
#define NEG_SLOPE 0.2f

// ---------------- small precompute: wc = fold(W_dst, a_dst) ----------------
__global__ void wc1_kernel(const float* __restrict__ W1_dst,
                           const float* __restrict__ a1_dst,
                           float* __restrict__ wc1) {
    int i = blockIdx.x * blockDim.x + threadIdx.x;
    if (i >= 128 * 8) return;
    int k = i >> 3, h = i & 7;
    float s = 0.f;
#pragma unroll
    for (int c = 0; c < 32; ++c)
        s += W1_dst[k * 256 + h * 32 + c] * a1_dst[h * 32 + c];
    wc1[i] = s;
}

__global__ void wc2_kernel(const float* __restrict__ W2_dst,
                           const float* __restrict__ a2_dst,
                           float* __restrict__ wc2) {
    int k = blockIdx.x * blockDim.x + threadIdx.x;
    if (k >= 256) return;
    float s = 0.f;
#pragma unroll
    for (int c = 0; c < 32; ++c)
        s += W2_dst[k * 32 + c] * a2_dst[c];
    wc2[k] = s;
}

// ---------------- CSR build --------------------------------------------------
__global__ __launch_bounds__(256) void hist_kernel(
    const int* __restrict__ dst, int* __restrict__ deg, int E) {
    int e = blockIdx.x * blockDim.x + threadIdx.x;
    if (e < E) atomicAdd(&deg[dst[e]], 1);
}

// block-level inclusive scan (256 elems/block)
__global__ __launch_bounds__(256) void scan_block(
    const int* __restrict__ deg, int* __restrict__ incl,
    int* __restrict__ bsum, int n) {
    __shared__ int sh[256];
    int tid = threadIdx.x;
    int i = blockIdx.x * 256 + tid;
    sh[tid] = (i < n) ? deg[i] : 0;
    __syncthreads();
    for (int off = 1; off < 256; off <<= 1) {
        int t = (tid >= off) ? sh[tid - off] : 0;
        __syncthreads();
        sh[tid] += t;
        __syncthreads();
    }
    if (i < n) incl[i] = sh[tid];
    if (tid == 255) bsum[blockIdx.x] = sh[255];
}

// exclusive scan of block sums (<=256 blocks) in one block
__global__ __launch_bounds__(256) void scan_top(
    const int* __restrict__ bsum, int* __restrict__ boff, int nb) {
    __shared__ int sh[256];
    int tid = threadIdx.x;
    sh[tid] = (tid < nb) ? bsum[tid] : 0;
    __syncthreads();
    for (int off = 1; off < 256; off <<= 1) {
        int t = (tid >= off) ? sh[tid - off] : 0;
        __syncthreads();
        sh[tid] += t;
        __syncthreads();
    }
    // exclusive = inclusive - own
    boff[tid] = sh[tid] - ((tid < nb) ? bsum[tid] : 0);
}

__global__ __launch_bounds__(256) void rs_kernel(
    const int* __restrict__ incl, const int* __restrict__ deg,
    const int* __restrict__ boff, int* __restrict__ rs,
    int* __restrict__ cursor, int n) {
    int i = blockIdx.x * blockDim.x + threadIdx.x;
    if (i >= n) return;
    int v = incl[i] - deg[i] + boff[i >> 8];
    rs[i] = v;
    cursor[i] = v;
}

__global__ __launch_bounds__(256) void fill_kernel(
    const int* __restrict__ src, const int* __restrict__ dst,
    int* __restrict__ cursor, int* __restrict__ csr_src, int E) {
    int e = blockIdx.x * blockDim.x + threadIdx.x;
    if (e >= E) return;
    int d = dst[e];
    int pos = atomicAdd(&cursor[d], 1);
    csr_src[pos] = src[e];
}

// ---------------- GEMM1: hs1 = x @ W1_src, + alpha_s1, alpha_d1 ------------
__global__ __launch_bounds__(256) void gemm1_kernel(
    const float* __restrict__ x, const float* __restrict__ W,
    const float* __restrict__ a_src, const float* __restrict__ wc1,
    float* __restrict__ hs1, float* __restrict__ alpha_s,
    float* __restrict__ alpha_d, int n) {
    __shared__ float xs[4][128];
    int node0 = blockIdx.x * 4;
    int tid = threadIdx.x;
    for (int i = tid; i < 4 * 128; i += 256) {
        int j = i >> 7, k = i & 127;
        int nn = node0 + j;
        xs[j][k] = (nn < n) ? x[(size_t)nn * 128 + k] : 0.f;
    }
    __syncthreads();
    float acc[4] = {0.f, 0.f, 0.f, 0.f};
    int c = tid;
#pragma unroll 8
    for (int k = 0; k < 128; ++k) {
        float w = W[k * 256 + c];
        acc[0] += xs[0][k] * w;
        acc[1] += xs[1][k] * w;
        acc[2] += xs[2][k] * w;
        acc[3] += xs[3][k] * w;
    }
    int h = c >> 5, cc = c & 31;
    float a = a_src[h * 32 + cc];
#pragma unroll
    for (int j = 0; j < 4; ++j) {
        int nn = node0 + j;
        if (nn < n) hs1[(size_t)nn * 256 + c] = acc[j];
        float p = acc[j] * a;
        for (int off = 16; off > 0; off >>= 1) p += __shfl_down(p, off, 32);
        if (cc == 0 && nn < n) alpha_s[nn * 8 + h] = p;
    }
    if (tid < 32) {
        int j = tid >> 3, hh = tid & 7;
        int nn = node0 + j;
        if (nn < n) {
            float s = 0.f;
            for (int k = 0; k < 128; ++k) s += xs[j][k] * wc1[k * 8 + hh];
            alpha_d[nn * 8 + hh] = s;
        }
    }
}

// ---------------- fused gather-aggregate layer 1 ---------------------------
// one 64-lane wave per destination node; lane L owns channels 4L..4L+3
// (head = L>>3). Computes softmax weight on the fly; num+denom in registers;
// writes final h1 = relu(num/denom + b1).
__global__ __launch_bounds__(256) void gather1(
    const int* __restrict__ csr_src, const int* __restrict__ rs,
    const int* __restrict__ deg, const float* __restrict__ hs1,
    const float* __restrict__ as1, const float* __restrict__ ad1,
    const float* __restrict__ b1, float* __restrict__ h1, int n) {
    int gid = blockIdx.x * blockDim.x + threadIdx.x;
    int node = gid >> 6;
    int lane = threadIdx.x & 63;
    if (node >= n) return;
    int h = lane >> 3;
    float ad_v = ad1[node * 8 + h];
    int start = rs[node], cnt = deg[node];
    const float4* hs4 = (const float4*)hs1;
    float4 acc = make_float4(0.f, 0.f, 0.f, 0.f);
    float dacc = 0.f;
    int i = 0;
    for (; i + 1 < cnt; i += 2) {
        int s0 = csr_src[start + i];
        int s1 = csr_src[start + i + 1];
        float t0 = as1[s0 * 8 + h] + ad_v;
        float t1 = as1[s1 * 8 + h] + ad_v;
        float4 v0 = hs4[(size_t)s0 * 64 + lane];
        float4 v1 = hs4[(size_t)s1 * 64 + lane];
        t0 = (t0 >= 0.f) ? t0 : NEG_SLOPE * t0;
        t1 = (t1 >= 0.f) ? t1 : NEG_SLOPE * t1;
        float w0 = __expf(t0);
        float w1 = __expf(t1);
        acc.x += v0.x * w0 + v1.x * w1;
        acc.y += v0.y * w0 + v1.y * w1;
        acc.z += v0.z * w0 + v1.z * w1;
        acc.w += v0.w * w0 + v1.w * w1;
        dacc += w0 + w1;
    }
    if (i < cnt) {
        int s0 = csr_src[start + i];
        float t0 = as1[s0 * 8 + h] + ad_v;
        float4 v0 = hs4[(size_t)s0 * 64 + lane];
        t0 = (t0 >= 0.f) ? t0 : NEG_SLOPE * t0;
        float w0 = __expf(t0);
        acc.x += v0.x * w0;
        acc.y += v0.y * w0;
        acc.z += v0.z * w0;
        acc.w += v0.w * w0;
        dacc += w0;
    }
    float inv = 1.f / (dacc + 1e-16f);
    float4 bv = ((const float4*)b1)[lane];
    float4 o;
    o.x = fmaxf(fmaf(acc.x, inv, bv.x), 0.f);
    o.y = fmaxf(fmaf(acc.y, inv, bv.y), 0.f);
    o.z = fmaxf(fmaf(acc.z, inv, bv.z), 0.f);
    o.w = fmaxf(fmaf(acc.w, inv, bv.w), 0.f);
    ((float4*)h1)[(size_t)node * 64 + lane] = o;
}

// ---------------- GEMM2: hs2 = h1 @ W2_src, + alpha_s2, alpha_d2 -----------
__global__ __launch_bounds__(256) void gemm2_kernel(
    const float* __restrict__ h1, const float* __restrict__ W2,
    const float* __restrict__ a2_src, const float* __restrict__ wc2,
    float* __restrict__ hs2, float* __restrict__ alpha_s2,
    float* __restrict__ alpha_d2, int n) {
    __shared__ float xs[8][256];
    int node0 = blockIdx.x * 8;
    int tid = threadIdx.x;
    for (int i = tid; i < 8 * 256; i += 256) {
        int j = i >> 8, k = i & 255;
        int nn = node0 + j;
        xs[j][k] = (nn < n) ? h1[(size_t)nn * 256 + k] : 0.f;
    }
    __syncthreads();
    int j = tid >> 5, c = tid & 31;
    float acc = 0.f;
#pragma unroll 8
    for (int k = 0; k < 256; ++k) acc += xs[j][k] * W2[k * 32 + c];
    int nn = node0 + j;
    if (nn < n) hs2[(size_t)nn * 32 + c] = acc;
    float p = acc * a2_src[c];
    for (int off = 16; off > 0; off >>= 1) p += __shfl_down(p, off, 32);
    if (c == 0 && nn < n) alpha_s2[nn] = p;
    if (tid < 8) {
        int n2 = node0 + tid;
        if (n2 < n) {
            float s = 0.f;
            for (int k = 0; k < 256; ++k) s += xs[tid][k] * wc2[k];
            alpha_d2[n2] = s;
        }
    }
}

// ---------------- fused gather-aggregate layer 2 (heads=1, C=32) -----------
// one wave per node; lanes 0-31 process even edges, 32-63 odd edges;
// channel = lane & 31; halves combined by shfl_xor(32).
__global__ __launch_bounds__(256) void gather2(
    const int* __restrict__ csr_src, const int* __restrict__ rs,
    const int* __restrict__ deg, const float* __restrict__ hs2,
    const float* __restrict__ as2, const float* __restrict__ ad2,
    const float* __restrict__ b2, float* __restrict__ out, int n) {
    int gid = blockIdx.x * blockDim.x + threadIdx.x;
    int node = gid >> 6;
    int lane = threadIdx.x & 63;
    if (node >= n) return;
    int c = lane & 31;
    int j = lane >> 5;
    float ad_v = ad2[node];
    int start = rs[node], cnt = deg[node];
    float acc = 0.f, dacc = 0.f;
    for (int i = j; i < cnt; i += 2) {
        int s = csr_src[start + i];
        float t = as2[s] + ad_v;
        t = (t >= 0.f) ? t : NEG_SLOPE * t;
        float w = __expf(t);
        acc += hs2[(size_t)s * 32 + c] * w;
        dacc += w;
    }
    acc += __shfl_xor(acc, 32, 64);
    dacc += __shfl_xor(dacc, 32, 64);
    if (j == 0)
        out[(size_t)node * 32 + c] = acc / (dacc + 1e-16f) + b2[c];
}

extern "C" void kernel_launch(void* const* d_in, const int* in_sizes, int n_in,
                              void* d_out, int out_size, void* d_ws, size_t ws_size,
                              hipStream_t stream) {
    const float* x      = (const float*)d_in[0];
    const int*   eidx   = (const int*)d_in[1];
    const float* W1_src = (const float*)d_in[2];
    const float* W1_dst = (const float*)d_in[3];
    const float* a1_src = (const float*)d_in[4];
    const float* a1_dst = (const float*)d_in[5];
    const float* b1     = (const float*)d_in[6];
    const float* W2_src = (const float*)d_in[7];
    const float* W2_dst = (const float*)d_in[8];
    const float* a2_src = (const float*)d_in[9];
    const float* a2_dst = (const float*)d_in[10];
    const float* b2     = (const float*)d_in[11];

    const int n = in_sizes[0] / D_IN;   // 50000
    const int E = in_sizes[1] / 2;      // 800000
    const int* src = eidx;
    const int* dst = eidx + E;
    const int nb = (n + 255) / 256;     // scan blocks (196)

    float* ws = (float*)d_ws;
    size_t o = 0;
    float* hs1 = ws + o; o += (size_t)n * 256;
    float* h1  = ws + o; o += (size_t)n * 256;
    float* as1 = ws + o; o += (size_t)n * 8;
    float* ad1 = ws + o; o += (size_t)n * 8;
    float* wc1 = ws + o; o += 1024;
    float* hs2 = ws + o; o += (size_t)n * 32;
    float* as2 = ws + o; o += (size_t)n;
    float* ad2 = ws + o; o += (size_t)n;
    float* wc2 = ws + o; o += 256;
    int* ip = (int*)(ws + o);
    size_t io = 0;
    int* deg     = ip + io; io += n;
    int* incl    = ip + io; io += n;
    int* bsum    = ip + io; io += 256;
    int* boff    = ip + io; io += 256;
    int* rs      = ip + io; io += n;
    int* cursor  = ip + io; io += n;
    int* csr_src = ip + io; io += E;

    hipMemsetAsync(deg, 0, (size_t)n * sizeof(int), stream);

    // CSR build
    hist_kernel<<<(E + 255) / 256, 256, 0, stream>>>(dst, deg, E);
    scan_block<<<nb, 256, 0, stream>>>(deg, incl, bsum, n);
    scan_top<<<1, 256, 0, stream>>>(bsum, boff, nb);
    rs_kernel<<<nb, 256, 0, stream>>>(incl, deg, boff, rs, cursor, n);
    fill_kernel<<<(E + 255) / 256, 256, 0, stream>>>(src, dst, cursor, csr_src, E);

    // weight folds
    wc1_kernel<<<4, 256, 0, stream>>>(W1_dst, a1_dst, wc1);
    wc2_kernel<<<1, 256, 0, stream>>>(W2_dst, a2_dst, wc2);

    // layer 1
    gemm1_kernel<<<(n + 3) / 4, 256, 0, stream>>>(x, W1_src, a1_src, wc1,
                                                  hs1, as1, ad1, n);
    gather1<<<(n + 3) / 4, 256, 0, stream>>>(csr_src, rs, deg, hs1, as1, ad1,
                                             b1, h1, n);

    // layer 2
    gemm2_kernel<<<(n + 7) / 8, 256, 0, stream>>>(h1, W2_src, a2_src, wc2,
                                                  hs2, as2, ad2, n);
    gather2<<<(n + 3) / 4, 256, 0, stream>>>(csr_src, rs, deg, hs2, as2, ad2,
                                             b2, (float*)d_out, n);
}

// Round 3
// 399.610 us; speedup vs baseline: 8.4913x; 1.2348x over previous
//
#include <hip/hip_runtime.h>
#include <hip/hip_bf16.h>

#define NEG_SLOPE 0.2f

typedef unsigned int uint;
typedef unsigned short ushort;

static __device__ __forceinline__ ushort f2bf(float f) {
    uint u = __float_as_uint(f);
    uint r = (u + 0x7fffu + ((u >> 16) & 1u)) >> 16;  // round-to-nearest-even
    return (ushort)r;
}
static __device__ __forceinline__ float bf2f(uint s) {
    return __uint_as_float(s << 16);
}

// ---------------- folded dst-attention weights -----------------------------
// wc1[k][h] = sum_c W1_dst[k][h*32+c]*a1_dst[h][c]; wc2[k] = sum_c W2_dst[k][c]*a2_dst[c]
__global__ __launch_bounds__(256) void wc_kernel(
    const float* __restrict__ W1_dst, const float* __restrict__ a1_dst,
    float* __restrict__ wc1,
    const float* __restrict__ W2_dst, const float* __restrict__ a2_dst,
    float* __restrict__ wc2) {
    int i = blockIdx.x * blockDim.x + threadIdx.x;
    if (i < 1024) {
        int k = i >> 3, h = i & 7;
        float s = 0.f;
#pragma unroll
        for (int c = 0; c < 32; ++c)
            s += W1_dst[k * 256 + h * 32 + c] * a1_dst[h * 32 + c];
        wc1[i] = s;
    } else if (i < 1280) {
        int k = i - 1024;
        float s = 0.f;
#pragma unroll
        for (int c = 0; c < 32; ++c)
            s += W2_dst[k * 32 + c] * a2_dst[c];
        wc2[k] = s;
    }
}

// ---------------- CSR build ------------------------------------------------
__global__ __launch_bounds__(256) void hist_kernel(
    const int* __restrict__ dst, int* __restrict__ deg, int E) {
    int e = blockIdx.x * blockDim.x + threadIdx.x;
    if (e < E) atomicAdd(&deg[dst[e]], 1);
}

__global__ __launch_bounds__(256) void scan_block(
    const int* __restrict__ deg, int* __restrict__ incl,
    int* __restrict__ bsum, int n) {
    __shared__ int sh[256];
    int tid = threadIdx.x;
    int i = blockIdx.x * 256 + tid;
    sh[tid] = (i < n) ? deg[i] : 0;
    __syncthreads();
    for (int off = 1; off < 256; off <<= 1) {
        int t = (tid >= off) ? sh[tid - off] : 0;
        __syncthreads();
        sh[tid] += t;
        __syncthreads();
    }
    if (i < n) incl[i] = sh[tid];
    if (tid == 255) bsum[blockIdx.x] = sh[255];
}

__global__ __launch_bounds__(256) void scan_top(
    const int* __restrict__ bsum, int* __restrict__ boff, int nb) {
    __shared__ int sh[256];
    int tid = threadIdx.x;
    sh[tid] = (tid < nb) ? bsum[tid] : 0;
    __syncthreads();
    for (int off = 1; off < 256; off <<= 1) {
        int t = (tid >= off) ? sh[tid - off] : 0;
        __syncthreads();
        sh[tid] += t;
        __syncthreads();
    }
    boff[tid] = sh[tid] - ((tid < nb) ? bsum[tid] : 0);
}

__global__ __launch_bounds__(256) void rs_kernel(
    const int* __restrict__ incl, const int* __restrict__ deg,
    const int* __restrict__ boff, int* __restrict__ rs,
    int* __restrict__ cursor, int n) {
    int i = blockIdx.x * blockDim.x + threadIdx.x;
    if (i >= n) return;
    int v = incl[i] - deg[i] + boff[i >> 8];
    rs[i] = v;
    cursor[i] = v;
}

__global__ __launch_bounds__(256) void fill_kernel(
    const int* __restrict__ src, const int* __restrict__ dst,
    int* __restrict__ cursor, int* __restrict__ csr_src, int E) {
    int e = blockIdx.x * blockDim.x + threadIdx.x;
    if (e >= E) return;
    int d = dst[e];
    int pos = atomicAdd(&cursor[d], 1);
    csr_src[pos] = src[e];
}

// ---------------- GEMM1: hs1b = bf16(x @ W1_src), alpha_s1, alpha_d1 -------
// 16 nodes/block. Thread (cg,jg): 4 cols (cg*4..) x 4 nodes (jg*4..) patch.
// Per k: 1 coalesced float4 W load + 1 broadcast ds_read_b128 -> 16 FMA.
__global__ __launch_bounds__(256) void gemm1_kernel(
    const float* __restrict__ x, const float* __restrict__ W,
    const float* __restrict__ a_src, const float* __restrict__ wc1,
    ushort* __restrict__ hs1b, float* __restrict__ alpha_s,
    float* __restrict__ alpha_d, int n) {
    __shared__ float xs_t[128][20];  // transposed; stride 20: b128-aligned, 8-way wr conflict
    int node0 = blockIdx.x * 16;
    int tid = threadIdx.x;
    for (int idx = tid; idx < 16 * 128; idx += 256) {
        int j = idx >> 7, k = idx & 127;
        int nn = node0 + j;
        xs_t[k][j] = (nn < n) ? x[(size_t)nn * 128 + k] : 0.f;
    }
    __syncthreads();
    int cg = tid & 63;   // column group: cols cg*4..cg*4+3 (head = cg>>3)
    int jg = tid >> 6;   // node group: nodes jg*4..jg*4+3
    float4 acc0 = {0, 0, 0, 0}, acc1 = {0, 0, 0, 0};
    float4 acc2 = {0, 0, 0, 0}, acc3 = {0, 0, 0, 0};
    const float4* W4 = (const float4*)W;
#pragma unroll 4
    for (int k = 0; k < 128; ++k) {
        float4 w = W4[k * 64 + cg];
        float4 xn = *(const float4*)&xs_t[k][jg * 4];
        acc0.x += w.x * xn.x; acc0.y += w.y * xn.x; acc0.z += w.z * xn.x; acc0.w += w.w * xn.x;
        acc1.x += w.x * xn.y; acc1.y += w.y * xn.y; acc1.z += w.z * xn.y; acc1.w += w.w * xn.y;
        acc2.x += w.x * xn.z; acc2.y += w.y * xn.z; acc2.z += w.z * xn.z; acc2.w += w.w * xn.z;
        acc3.x += w.x * xn.w; acc3.y += w.y * xn.w; acc3.z += w.z * xn.w; acc3.w += w.w * xn.w;
    }
    float4 a4 = ((const float4*)a_src)[cg];
    int h = cg >> 3;
    auto epi = [&](float4 av, int jj) {
        int nn = node0 + jg * 4 + jj;
        float p = av.x * a4.x + av.y * a4.y + av.z * a4.z + av.w * a4.w;
        p += __shfl_down(p, 4, 8);
        p += __shfl_down(p, 2, 8);
        p += __shfl_down(p, 1, 8);
        if (nn < n) {
            uint2 pk;
            pk.x = (uint)f2bf(av.x) | ((uint)f2bf(av.y) << 16);
            pk.y = (uint)f2bf(av.z) | ((uint)f2bf(av.w) << 16);
            *(uint2*)(hs1b + (size_t)nn * 256 + cg * 4) = pk;
            if ((cg & 7) == 0) alpha_s[nn * 8 + h] = p;
        }
    };
    epi(acc0, 0); epi(acc1, 1); epi(acc2, 2); epi(acc3, 3);
    // alpha_d: 16 nodes x 8 heads on threads 0..127
    if (tid < 128) {
        int j = tid >> 3, hh = tid & 7;
        int nn = node0 + j;
        if (nn < n) {
            float s = 0.f;
            for (int k = 0; k < 128; ++k) s += xs_t[k][j] * wc1[k * 8 + hh];
            alpha_d[nn * 8 + hh] = s;
        }
    }
}

// ---------------- fused gather-aggregate layer 1 (bf16 rows) ---------------
// one wave per node, 2 edges in flight. half-wave lane l owns channels
// l*8..l*8+7 (one uint4 = 16B of bf16), head = l>>2. Result h1 stored bf16.
__global__ __launch_bounds__(256) void gather1(
    const int* __restrict__ csr_src, const int* __restrict__ rs,
    const int* __restrict__ deg, const ushort* __restrict__ hs1b,
    const float* __restrict__ as1, const float* __restrict__ ad1,
    const float* __restrict__ b1, ushort* __restrict__ h1b, int n) {
    int gid = blockIdx.x * blockDim.x + threadIdx.x;
    int node = gid >> 6;
    int lane = threadIdx.x & 63;
    if (node >= n) return;
    int j = lane >> 5, l = lane & 31;
    int h = l >> 2;
    float ad_v = ad1[node * 8 + h];
    int start = rs[node], cnt = deg[node];
    float acc0 = 0.f, acc1 = 0.f, acc2 = 0.f, acc3 = 0.f;
    float acc4 = 0.f, acc5 = 0.f, acc6 = 0.f, acc7 = 0.f;
    float dacc = 0.f;
    for (int i = j; i < cnt; i += 2) {
        int s = csr_src[start + i];
        float t = as1[s * 8 + h] + ad_v;
        t = (t >= 0.f) ? t : NEG_SLOPE * t;
        float w = __expf(t);
        uint4 v = *(const uint4*)(hs1b + (size_t)s * 256 + l * 8);
        acc0 += bf2f(v.x & 0xffffu) * w;
        acc1 += bf2f(v.x >> 16) * w;
        acc2 += bf2f(v.y & 0xffffu) * w;
        acc3 += bf2f(v.y >> 16) * w;
        acc4 += bf2f(v.z & 0xffffu) * w;
        acc5 += bf2f(v.z >> 16) * w;
        acc6 += bf2f(v.w & 0xffffu) * w;
        acc7 += bf2f(v.w >> 16) * w;
        dacc += w;
    }
    acc0 += __shfl_xor(acc0, 32, 64);
    acc1 += __shfl_xor(acc1, 32, 64);
    acc2 += __shfl_xor(acc2, 32, 64);
    acc3 += __shfl_xor(acc3, 32, 64);
    acc4 += __shfl_xor(acc4, 32, 64);
    acc5 += __shfl_xor(acc5, 32, 64);
    acc6 += __shfl_xor(acc6, 32, 64);
    acc7 += __shfl_xor(acc7, 32, 64);
    dacc += __shfl_xor(dacc, 32, 64);
    if (j == 0) {
        float inv = 1.f / (dacc + 1e-16f);
        float4 b0 = ((const float4*)b1)[l * 2];
        float4 b4 = ((const float4*)b1)[l * 2 + 1];
        float o0 = fmaxf(fmaf(acc0, inv, b0.x), 0.f);
        float o1 = fmaxf(fmaf(acc1, inv, b0.y), 0.f);
        float o2 = fmaxf(fmaf(acc2, inv, b0.z), 0.f);
        float o3 = fmaxf(fmaf(acc3, inv, b0.w), 0.f);
        float o4 = fmaxf(fmaf(acc4, inv, b4.x), 0.f);
        float o5 = fmaxf(fmaf(acc5, inv, b4.y), 0.f);
        float o6 = fmaxf(fmaf(acc6, inv, b4.z), 0.f);
        float o7 = fmaxf(fmaf(acc7, inv, b4.w), 0.f);
        uint4 pk;
        pk.x = (uint)f2bf(o0) | ((uint)f2bf(o1) << 16);
        pk.y = (uint)f2bf(o2) | ((uint)f2bf(o3) << 16);
        pk.z = (uint)f2bf(o4) | ((uint)f2bf(o5) << 16);
        pk.w = (uint)f2bf(o6) | ((uint)f2bf(o7) << 16);
        *(uint4*)(h1b + (size_t)node * 256 + l * 8) = pk;
    }
}

// ---------------- GEMM2: hs2b = bf16(h1 @ W2_src), alpha_s2, alpha_d2 ------
// 32 nodes/block. Thread (c,jg): col c, nodes jg*4..jg*4+3.
__global__ __launch_bounds__(256) void gemm2_kernel(
    const ushort* __restrict__ h1b, const float* __restrict__ W2,
    const float* __restrict__ a2_src, const float* __restrict__ wc2,
    ushort* __restrict__ hs2b, float* __restrict__ alpha_s2,
    float* __restrict__ alpha_d2, int n) {
    __shared__ float hs_t[256][36];  // transposed; stride 36: b128-aligned
    int node0 = blockIdx.x * 32;
    int tid = threadIdx.x;
    for (int idx = tid; idx < 32 * 128; idx += 256) {
        int j = idx >> 7, k2 = idx & 127;
        int nn = node0 + j;
        uint v = (nn < n) ? *(const uint*)(h1b + (size_t)nn * 256 + k2 * 2) : 0u;
        hs_t[k2 * 2][j] = bf2f(v & 0xffffu);
        hs_t[k2 * 2 + 1][j] = bf2f(v >> 16);
    }
    __syncthreads();
    int c = tid & 31, jg = tid >> 5;
    float acc0 = 0.f, acc1 = 0.f, acc2 = 0.f, acc3 = 0.f;
#pragma unroll 4
    for (int k = 0; k < 256; ++k) {
        float w = W2[k * 32 + c];
        float4 xn = *(const float4*)&hs_t[k][jg * 4];
        acc0 += w * xn.x;
        acc1 += w * xn.y;
        acc2 += w * xn.z;
        acc3 += w * xn.w;
    }
    float a = a2_src[c];
    auto epi = [&](float av, int jj) {
        int nn = node0 + jg * 4 + jj;
        float p = av * a;
        p += __shfl_down(p, 16, 32);
        p += __shfl_down(p, 8, 32);
        p += __shfl_down(p, 4, 32);
        p += __shfl_down(p, 2, 32);
        p += __shfl_down(p, 1, 32);
        if (nn < n) {
            hs2b[(size_t)nn * 32 + c] = f2bf(av);
            if (c == 0) alpha_s2[nn] = p;
        }
    };
    epi(acc0, 0); epi(acc1, 1); epi(acc2, 2); epi(acc3, 3);
    if (tid < 32) {
        int nn = node0 + tid;
        if (nn < n) {
            float s = 0.f;
            for (int k = 0; k < 256; ++k) s += hs_t[k][tid] * wc2[k];
            alpha_d2[nn] = s;
        }
    }
}

// ---------------- fused gather-aggregate layer 2 (bf16 rows) ---------------
// one wave per node, 4 edges in flight; 16-lane group per edge, lane owns
// 2 channels (one uint).
__global__ __launch_bounds__(256) void gather2(
    const int* __restrict__ csr_src, const int* __restrict__ rs,
    const int* __restrict__ deg, const ushort* __restrict__ hs2b,
    const float* __restrict__ as2, const float* __restrict__ ad2,
    const float* __restrict__ b2, float* __restrict__ out, int n) {
    int gid = blockIdx.x * blockDim.x + threadIdx.x;
    int node = gid >> 6;
    int lane = threadIdx.x & 63;
    if (node >= n) return;
    int j = lane >> 4, l = lane & 15;
    float ad_v = ad2[node];
    int start = rs[node], cnt = deg[node];
    float accx = 0.f, accy = 0.f, dacc = 0.f;
    for (int i = j; i < cnt; i += 4) {
        int s = csr_src[start + i];
        float t = as2[s] + ad_v;
        t = (t >= 0.f) ? t : NEG_SLOPE * t;
        float w = __expf(t);
        uint v = *(const uint*)(hs2b + (size_t)s * 32 + l * 2);
        accx += bf2f(v & 0xffffu) * w;
        accy += bf2f(v >> 16) * w;
        dacc += w;
    }
    accx += __shfl_xor(accx, 32, 64);
    accy += __shfl_xor(accy, 32, 64);
    dacc += __shfl_xor(dacc, 32, 64);
    accx += __shfl_xor(accx, 16, 64);
    accy += __shfl_xor(accy, 16, 64);
    dacc += __shfl_xor(dacc, 16, 64);
    if (lane < 16) {
        float inv = 1.f / (dacc + 1e-16f);
        float2 bv = ((const float2*)b2)[l];
        float2 o;
        o.x = fmaf(accx, inv, bv.x);
        o.y = fmaf(accy, inv, bv.y);
        *(float2*)(out + (size_t)node * 32 + l * 2) = o;
    }
}

extern "C" void kernel_launch(void* const* d_in, const int* in_sizes, int n_in,
                              void* d_out, int out_size, void* d_ws, size_t ws_size,
                              hipStream_t stream) {
    const float* x      = (const float*)d_in[0];
    const int*   eidx   = (const int*)d_in[1];
    const float* W1_src = (const float*)d_in[2];
    const float* W1_dst = (const float*)d_in[3];
    const float* a1_src = (const float*)d_in[4];
    const float* a1_dst = (const float*)d_in[5];
    const float* b1     = (const float*)d_in[6];
    const float* W2_src = (const float*)d_in[7];
    const float* W2_dst = (const float*)d_in[8];
    const float* a2_src = (const float*)d_in[9];
    const float* a2_dst = (const float*)d_in[10];
    const float* b2     = (const float*)d_in[11];

    const int n = in_sizes[0] / 128;    // 50000
    const int E = in_sizes[1] / 2;      // 800000
    const int* src = eidx;
    const int* dst = eidx + E;
    const int nb = (n + 255) / 256;

    char* ws = (char*)d_ws;
    size_t o = 0;
    auto alloc = [&](size_t bytes) {
        void* p = ws + o;
        o += (bytes + 255) & ~(size_t)255;
        return p;
    };
    ushort* hs1b = (ushort*)alloc((size_t)n * 256 * 2);
    ushort* h1b  = (ushort*)alloc((size_t)n * 256 * 2);
    ushort* hs2b = (ushort*)alloc((size_t)n * 32 * 2);
    float* as1 = (float*)alloc((size_t)n * 8 * 4);
    float* ad1 = (float*)alloc((size_t)n * 8 * 4);
    float* as2 = (float*)alloc((size_t)n * 4);
    float* ad2 = (float*)alloc((size_t)n * 4);
    float* wc1 = (float*)alloc(1024 * 4);
    float* wc2 = (float*)alloc(256 * 4);
    int* deg     = (int*)alloc((size_t)n * 4);
    int* incl    = (int*)alloc((size_t)n * 4);
    int* bsum    = (int*)alloc(256 * 4);
    int* boff    = (int*)alloc(256 * 4);
    int* rs      = (int*)alloc((size_t)n * 4);
    int* cursor  = (int*)alloc((size_t)n * 4);
    int* csr_src = (int*)alloc((size_t)E * 4);

    hipMemsetAsync(deg, 0, (size_t)n * sizeof(int), stream);

    // CSR build
    hist_kernel<<<(E + 255) / 256, 256, 0, stream>>>(dst, deg, E);
    scan_block<<<nb, 256, 0, stream>>>(deg, incl, bsum, n);
    scan_top<<<1, 256, 0, stream>>>(bsum, boff, nb);
    rs_kernel<<<nb, 256, 0, stream>>>(incl, deg, boff, rs, cursor, n);
    fill_kernel<<<(E + 255) / 256, 256, 0, stream>>>(src, dst, cursor, csr_src, E);

    wc_kernel<<<5, 256, 0, stream>>>(W1_dst, a1_dst, wc1, W2_dst, a2_dst, wc2);

    // layer 1
    gemm1_kernel<<<(n + 15) / 16, 256, 0, stream>>>(x, W1_src, a1_src, wc1,
                                                    hs1b, as1, ad1, n);
    gather1<<<(n + 3) / 4, 256, 0, stream>>>(csr_src, rs, deg, hs1b, as1, ad1,
                                             b1, h1b, n);

    // layer 2
    gemm2_kernel<<<(n + 31) / 32, 256, 0, stream>>>(h1b, W2_src, a2_src, wc2,
                                                    hs2b, as2, ad2, n);
    gather2<<<(n + 3) / 4, 256, 0, stream>>>(csr_src, rs, deg, hs2b, as2, ad2,
                                             b2, (float*)d_out, n);
}